// Round 14
// baseline (210.410 us; speedup 1.0000x reference)
//
#include <hip/hip_runtime.h>
#include <hip/hip_bf16.h>

#define DM 1024
#define NHEADS 16
#define DKH 64
#define BATCH 4
#define SEQ 2048
#define MROWS (BATCH*SEQ)   // 8192

typedef __attribute__((ext_vector_type(8))) short bf16x8;
typedef __attribute__((ext_vector_type(4))) short bf16x4;
typedef __attribute__((ext_vector_type(4))) float f32x4;
typedef __attribute__((ext_vector_type(16))) float f32x16;

#if __has_builtin(__builtin_amdgcn_exp2f)
#define EXP2(x) __builtin_amdgcn_exp2f(x)
#else
#define EXP2(x) exp2f(x)
#endif

__device__ __forceinline__ unsigned short f2bf(float f){
  unsigned u = __float_as_uint(f);
  u += 0x7fffu + ((u >> 16) & 1u);   // RNE
  return (unsigned short)(u >> 16);
}

__device__ __forceinline__ unsigned pk2bf(float lo, float hi){
  union { __hip_bfloat162 h; unsigned u; } c;
  c.h = __float22bfloat162_rn(make_float2(lo, hi));   // v_cvt_pk_bf16_f32 (RNE)
  return c.u;
}

__device__ __forceinline__ bf16x8 cvtA8(float4 a, float4 b){
  union { unsigned u[4]; bf16x8 v; } r;
  r.u[0] = pk2bf(a.x, a.y);
  r.u[1] = pk2bf(a.z, a.w);
  r.u[2] = pk2bf(b.x, b.y);
  r.u[3] = pk2bf(b.z, b.w);
  return r.v;
}

__device__ __forceinline__ void gload16(const unsigned short* g, unsigned short* l){
  __builtin_amdgcn_global_load_lds((const __attribute__((address_space(1))) void*)g,
                                   (__attribute__((address_space(3))) void*)l, 16, 0, 0);
}

// ---------------- fp32 -> bf16 conversion (4 weight matrices only) ----------------
struct ConvArgs { const float* src[4]; unsigned short* dst[4]; };

__global__ __launch_bounds__(256) void conv_w(ConvArgs a){
  const int t = blockIdx.x >> 10;          // 4 tensors x 1024 blocks
  const int boff = blockIdx.x & 1023;
  const float* __restrict__ src = a.src[t];
  unsigned short* __restrict__ dst = a.dst[t];
  const int i = (boff * 256 + threadIdx.x) * 4;
  const float4 v = *reinterpret_cast<const float4*>(src + i);
  ushort4 o;
  o.x = f2bf(v.x); o.y = f2bf(v.y); o.z = f2bf(v.z); o.w = f2bf(v.w);
  *reinterpret_cast<ushort4*>(dst + i) = o;
}

// ---------------- GEMM: C[m,n] = sum_k A[m,k]*W[n,k] + bias[n] ----------------
// ~880 TF each = the m97-structure ceiling for this 128^2 shape; accepted.
template<int MODE, int AFP32>
__global__ __launch_bounds__(256)
void gemm_bt(const void* __restrict__ Av, const unsigned short* __restrict__ Bw,
             const float* __restrict__ bias, void* __restrict__ out, float scale)
{
  const int K = 1024;
  __shared__ short a_sh[128*64];
  __shared__ short b_sh[128*64];
  const int tid  = threadIdx.x;
  const int lane = tid & 63;
  const int wid  = tid >> 6;
  const int wm = wid >> 1, wn = wid & 1;           // 2x2 waves -> 64x64 each
  const int lin = blockIdx.x;
  const int xcd = lin & 7;
  const int i9  = lin >> 3;
  const int tileM = (8*xcd + (i9 >> 3)) * 128;
  const int tileN = (i9 & 7) * 128;

  f32x4 acc[4][4];
  #pragma unroll
  for (int i = 0; i < 4; i++)
    #pragma unroll
    for (int j = 0; j < 4; j++)
      acc[i][j] = (f32x4){0.f,0.f,0.f,0.f};

  const int lr = lane & 15;
  const int lg = lane >> 4;
  const int r8 = lane >> 3, c8 = lane & 7;
  const int srow = 8*wid + r8;                 // + 32j per call
  const int sgrp = (c8 ^ r8) * 8;              // pre-swizzled source column group

  for (int k0 = 0; k0 < K; k0 += 64){
    bf16x8 ra[4];
    if constexpr (AFP32){
      const float* Af = (const float*)Av;
      #pragma unroll
      for (int i = 0; i < 4; i++){
        int v   = tid + 256*i;
        int row = v >> 3;
        int cg  = v & 7;
        const float4 f0 = *reinterpret_cast<const float4*>(Af + (size_t)(tileM+row)*K + k0 + cg*8);
        const float4 f1 = *reinterpret_cast<const float4*>(Af + (size_t)(tileM+row)*K + k0 + cg*8 + 4);
        ra[i] = cvtA8(f0, f1);
      }
    }
    __syncthreads();   // LDS free (consumers of previous tile done)
    #pragma unroll
    for (int j = 0; j < 4; j++){
      gload16(Bw + (size_t)(tileN + srow + 32*j)*K + k0 + sgrp,
              (unsigned short*)&b_sh[(8*wid + 32*j)*64]);
    }
    if constexpr (AFP32){
      #pragma unroll
      for (int i = 0; i < 4; i++){
        int v   = tid + 256*i;
        int row = v >> 3;
        int cg  = v & 7;
        *reinterpret_cast<bf16x8*>(&a_sh[row*64 + ((cg ^ (row & 7)) * 8)]) = ra[i];
      }
    } else {
      const unsigned short* Ab = (const unsigned short*)Av;
      #pragma unroll
      for (int j = 0; j < 4; j++){
        gload16(Ab + (size_t)(tileM + srow + 32*j)*K + k0 + sgrp,
                (unsigned short*)&a_sh[(8*wid + 32*j)*64]);
      }
    }
    __syncthreads();   // drains vmcnt (gload_lds) + lgkm (ds_write)

    #pragma unroll
    for (int kk = 0; kk < 64; kk += 32){
      bf16x8 af[4], bfr[4];
      const int g0 = lg + (kk >> 3);
      #pragma unroll
      for (int fm = 0; fm < 4; fm++){
        int row = wm*64 + fm*16 + lr;
        af[fm] = *reinterpret_cast<const bf16x8*>(&a_sh[row*64 + ((g0 ^ (row & 7)) * 8)]);
      }
      #pragma unroll
      for (int fn = 0; fn < 4; fn++){
        int row = wn*64 + fn*16 + lr;
        bfr[fn] = *reinterpret_cast<const bf16x8*>(&b_sh[row*64 + ((g0 ^ (row & 7)) * 8)]);
      }
      #pragma unroll
      for (int fm = 0; fm < 4; fm++)
        #pragma unroll
        for (int fn = 0; fn < 4; fn++)
          acc[fm][fn] = __builtin_amdgcn_mfma_f32_16x16x32_bf16(af[fm], bfr[fn], acc[fm][fn], 0, 0, 0);
    }
  }

  #pragma unroll
  for (int fm = 0; fm < 4; fm++){
    #pragma unroll
    for (int fn = 0; fn < 4; fn++){
      #pragma unroll
      for (int r = 0; r < 4; r++){
        int m = tileM + wm*64 + fm*16 + lg*4 + r;
        int n = tileN + wn*64 + fn*16 + lr;
        float val = acc[fm][fn][r] + bias[n];
        if (MODE == 0){
          val *= scale;
          int b = m >> 11, s = m & 2047, h = n >> 6, d = n & 63;
          ((unsigned short*)out)[(((size_t)(b*NHEADS + h)*SEQ + s)*DKH + d)] = f2bf(val);
        } else if (MODE == 1){
          int b = m >> 11, s = m & 2047, h = n >> 6, d = n & 63;
          ((unsigned short*)out)[(((size_t)(b*NHEADS + h)*DKH + d)*SEQ + s)] = f2bf(val);
        } else {
          ((float*)out)[(size_t)m*DM + n] = val;
        }
      }
    }
  }
}

// ---------------- flash attention (causal), 32x32 MFMA pipeline (r11 + softmax-path cuts) ----------------
// 512-thread block = 8 waves: waves 0-3 own qtile 15-y, waves 4-7 own qtile y.
// Each wave: 32 q-rows via 32x32x16 MFMA. Lane = one q column (lane&31); 16 C-regs
// hold 16 of 32 k-rows (partner lane^32 holds the rest). KVBLK=128 staged per epoch,
// processed as 4x 32-k chunks. exp2 domain; defer-max THR=8.
// NEW vs r11: (a) row-max is a 4-deep tree (was 15-deep serial chain — compiler
// can't reassociate fp without fast-math); (b) the cross-half shfl_xor(32) moved
// inside the rescale branch (wave-wide __any over half-maxes is equivalent to the
// vote over row-maxes, so common-path semantics are bit-identical).
__global__ __launch_bounds__(512, 2)
void attn_kernel(const unsigned short* __restrict__ Q, const unsigned short* __restrict__ Kb,
                 const unsigned short* __restrict__ Vt, unsigned short* __restrict__ Oout)
{
  __shared__ unsigned short k_sh[2][128*64];   // [k row][d], XOR-swizzled 16B groups
  __shared__ unsigned short v_sh[2][64*128];   // [d][k col], XOR-swizzled 16B groups
  const int lane = threadIdx.x & 63;
  const int w    = threadIdx.x >> 6;          // 0..7
  const int q32  = lane & 31;                 // lane's q column
  const int hi   = lane >> 5;                 // half-wave
  const int l7   = lane & 7;                  // swizzle XOR (row&7 == lane&7 for our reads)
  const int bh = blockIdx.x;                  // 0..63
  const int y  = (int)blockIdx.y;             // 0..7
  const int hiT = 15 - y;
  const int myTile = (w < 4) ? hiT : y;       // paired tiles per block
  const int qb0 = myTile * 128;
  const int qw0 = qb0 + (w & 3) * 32;         // wave's first q row
  const int qglob = qw0 + q32;
  const int b = bh >> 4, h = bh & 15;
  const size_t kbase = (size_t)bh * SEQ * DKH;
  const size_t vbase = (size_t)bh * DKH * SEQ;

  // K staging: wave w stages rows 16w..16w+15 (2 calls x 8 rows).
  const int r8 = lane >> 3, c8 = lane & 7;
  const size_t offK0 = (size_t)(16*w + r8)*DKH     + (size_t)((c8 ^ r8) * 8);
  const size_t offK1 = (size_t)(16*w + 8 + r8)*DKH + (size_t)((c8 ^ r8) * 8);
  const int ldsK0 = (16*w)*64, ldsK1 = (16*w + 8)*64;
  // V staging: wave w stages d-rows 8w..8w+7 (2 calls x 4 rows x 16 groups of 16B).
  const int r4 = lane >> 4, c16 = lane & 15;
  const size_t offV0 = (size_t)(8*w + r4)*SEQ     + (size_t)((c16 ^ r4) * 8);
  const size_t offV1 = (size_t)(8*w + 4 + r4)*SEQ + (size_t)((c16 ^ (4 + r4)) * 8);
  const int ldsV0 = (8*w)*128, ldsV1 = (8*w + 4)*128;

  // Q fragments: qf[dblk][j] = Q[qglob][dblk*16 + hi*8 + j]  (B-operand, 4 d-slices)
  bf16x8 qf[4];
  #pragma unroll
  for (int dblk = 0; dblk < 4; dblk++){
    qf[dblk] = *reinterpret_cast<const bf16x8*>(Q + kbase + (size_t)qglob*DKH + dblk*16 + hi*8);
  }

  float mrun = -__builtin_inff();
  float llocal = 0.f;
  f32x16 o0, o1;          // O^T[d][q]: d32-halves, 16 regs each
  #pragma unroll
  for (int r = 0; r < 16; r++){ o0[r] = 0.f; o1[r] = 0.f; }
  f32x16 zero16;
  #pragma unroll
  for (int r = 0; r < 16; r++) zero16[r] = 0.f;

  const int nkb = hiT + 1;   // 128-k epochs; block length set by the heavy tile

#define STAGE(kb_, bf_) do { \
    gload16(Kb + kbase + (size_t)(kb_)*8192 + offK0, (unsigned short*)&k_sh[bf_][ldsK0]); \
    gload16(Kb + kbase + (size_t)(kb_)*8192 + offK1, (unsigned short*)&k_sh[bf_][ldsK1]); \
    gload16(Vt + vbase + (size_t)(kb_)*128  + offV0, (unsigned short*)&v_sh[bf_][ldsV0]); \
    gload16(Vt + vbase + (size_t)(kb_)*128  + offV1, (unsigned short*)&v_sh[bf_][ldsV1]); \
  } while(0)

  STAGE(0, 0);
  __syncthreads();

  for (int kb = 0; kb < nkb; kb++){
    const int buf = kb & 1;
    if (kb + 1 < nkb) STAGE(kb + 1, buf ^ 1);

    const unsigned short* ks = k_sh[buf];
    const unsigned short* vs = v_sh[buf];

    #pragma unroll
    for (int c = 0; c < 4; c++){
      const int base_k = kb*128 + c*32;
      if (base_k <= qw0 + 31){
        // ---- QK^T: S^T[32k][32q] over d=64 (4 slices) ----
        f32x16 st;
        __builtin_amdgcn_s_setprio(1);
        {
          bf16x8 kf0 = *reinterpret_cast<const bf16x8*>(&ks[(c*32 + q32)*64 + ((hi ^ l7) * 8)]);
          st = __builtin_amdgcn_mfma_f32_32x32x16_bf16(kf0, qf[0], zero16, 0, 0, 0);
        }
        #pragma unroll
        for (int dblk = 1; dblk < 4; dblk++){
          bf16x8 kf = *reinterpret_cast<const bf16x8*>(&ks[(c*32 + q32)*64 + (((dblk*2 + hi) ^ l7) * 8)]);
          st = __builtin_amdgcn_mfma_f32_32x32x16_bf16(kf, qf[dblk], st, 0, 0, 0);
        }
        __builtin_amdgcn_s_setprio(0);

        // ---- causal mask (rare branch: only diagonal chunks) ----
        if (base_k + 31 > qw0){
          #pragma unroll
          for (int r = 0; r < 16; r++){
            int kg = base_k + (r & 3) + 8*(r >> 2) + 4*hi;
            if (kg > qglob) st[r] = -__builtin_inff();
          }
        }

        // ---- local half-row max: 4-deep tree (was 15-deep serial chain) ----
        float m0 = fmaxf(st[0],  st[1]),  m1 = fmaxf(st[2],  st[3]);
        float m2 = fmaxf(st[4],  st[5]),  m3 = fmaxf(st[6],  st[7]);
        float m4 = fmaxf(st[8],  st[9]),  m5 = fmaxf(st[10], st[11]);
        float m6 = fmaxf(st[12], st[13]), m7 = fmaxf(st[14], st[15]);
        float ma = fmaxf(m0, m1), mb = fmaxf(m2, m3);
        float mc = fmaxf(m4, m5), md = fmaxf(m6, m7);
        float mt = fmaxf(fmaxf(ma, mb), fmaxf(mc, md));

        // defer-max (T13): wave-wide vote over per-lane half-maxes is equivalent
        // to the vote over row-maxes; cross-half shfl only on the rescale path.
        if (__any(mt > mrun + 8.f)){
          const float mrow = fmaxf(mt, __shfl_xor(mt, 32));
          const float mnew = fmaxf(mrun, mrow);
          const float corr = EXP2(mrun - mnew);   // exp2(-inf)=0 at first chunk
          mrun = mnew;
          #pragma unroll
          for (int r = 0; r < 16; r++){ o0[r] *= corr; o1[r] *= corr; }
          llocal *= corr;
        }

        // ---- exp2 + lane-local l-sum + pack ----
        float p[16];
        #pragma unroll
        for (int r = 0; r < 16; r++) p[r] = EXP2(st[r] - mrun);
        {
          float s0 = (p[0]+p[1]) + (p[2]+p[3]);
          float s1 = (p[4]+p[5]) + (p[6]+p[7]);
          float s2 = (p[8]+p[9]) + (p[10]+p[11]);
          float s3 = (p[12]+p[13]) + (p[14]+p[15]);
          llocal += (s0+s1) + (s2+s3);
        }
        unsigned pkA0 = pk2bf(p[0],  p[1]),  pkA1 = pk2bf(p[2],  p[3]);
        unsigned pkB0 = pk2bf(p[4],  p[5]),  pkB1 = pk2bf(p[6],  p[7]);
        unsigned pkC0 = pk2bf(p[8],  p[9]),  pkC1 = pk2bf(p[10], p[11]);
        unsigned pkD0 = pk2bf(p[12], p[13]), pkD1 = pk2bf(p[14], p[15]);
        unsigned xA0 = __shfl_xor(pkA0, 32), xA1 = __shfl_xor(pkA1, 32);
        unsigned xB0 = __shfl_xor(pkB0, 32), xB1 = __shfl_xor(pkB1, 32);
        unsigned xC0 = __shfl_xor(pkC0, 32), xC1 = __shfl_xor(pkC1, 32);
        unsigned xD0 = __shfl_xor(pkD0, 32), xD1 = __shfl_xor(pkD1, 32);
        const bool lo = (hi == 0);
        union { unsigned u[4]; bf16x8 v; } f0, f1;
        // frag0 rows hi*8+j = k 0..15:  lo: own k0-3 (pkA) + partner k4-7 (xA)
        //                               hi: partner k8-11 (xB) + own k12-15 (pkB)
        f0.u[0] = lo ? pkA0 : xB0;
        f0.u[1] = lo ? pkA1 : xB1;
        f0.u[2] = lo ? xA0  : pkB0;
        f0.u[3] = lo ? xA1  : pkB1;
        // frag1 rows = k 16..31 (same pattern with C/D)
        f1.u[0] = lo ? pkC0 : xD0;
        f1.u[1] = lo ? pkC1 : xD1;
        f1.u[2] = lo ? xC0  : pkD0;
        f1.u[3] = lo ? xC1  : pkD1;

        // ---- PV: O^T[d][q] += V^T[d][k16] * P^T[k16][q], 2 k16 x 2 d32 ----
        __builtin_amdgcn_s_setprio(1);
        #pragma unroll
        for (int k16 = 0; k16 < 2; k16++){
          bf16x8 fr = k16 ? f1.v : f0.v;
          {
            bf16x8 vf = *reinterpret_cast<const bf16x8*>(
                &vs[(0*32 + q32)*128 + (((c*4 + k16*2 + hi) ^ l7) * 8)]);
            o0 = __builtin_amdgcn_mfma_f32_32x32x16_bf16(vf, fr, o0, 0, 0, 0);
          }
          {
            bf16x8 vf = *reinterpret_cast<const bf16x8*>(
                &vs[(1*32 + q32)*128 + (((c*4 + k16*2 + hi) ^ l7) * 8)]);
            o1 = __builtin_amdgcn_mfma_f32_32x32x16_bf16(vf, fr, o1, 0, 0, 0);
          }
        }
        __builtin_amdgcn_s_setprio(0);
      }
    }
    __syncthreads();
  }
#undef STAGE

  // ---- epilogue: lane owns q-row qglob; d = d32*32 + 8*(reg>>2) + 4*hi + (reg&3) ----
  const float l = llocal + __shfl_xor(llocal, 32);
  const float inv = 1.0f / l;
  size_t ob = ((size_t)(b*SEQ + qglob))*DM + h*DKH;
  #pragma unroll
  for (int g = 0; g < 4; g++){
    ushort4 pk;
    pk.x = f2bf(o0[4*g+0]*inv); pk.y = f2bf(o0[4*g+1]*inv);
    pk.z = f2bf(o0[4*g+2]*inv); pk.w = f2bf(o0[4*g+3]*inv);
    *reinterpret_cast<ushort4*>(&Oout[ob + 8*g + 4*hi]) = pk;
    ushort4 pk2;
    pk2.x = f2bf(o1[4*g+0]*inv); pk2.y = f2bf(o1[4*g+1]*inv);
    pk2.z = f2bf(o1[4*g+2]*inv); pk2.w = f2bf(o1[4*g+3]*inv);
    *reinterpret_cast<ushort4*>(&Oout[ob + 32 + 8*g + 4*hi]) = pk2;
  }
}

extern "C" void kernel_launch(void* const* d_in, const int* in_sizes, int n_in,
                              void* d_out, int out_size, void* d_ws, size_t ws_size,
                              hipStream_t stream) {
  const float* query = (const float*)d_in[0];
  const float* key   = (const float*)d_in[1];
  const float* value = (const float*)d_in[2];
  const float* Wq = (const float*)d_in[4];
  const float* bq = (const float*)d_in[5];
  const float* Wk = (const float*)d_in[6];
  const float* bk = (const float*)d_in[7];
  const float* Wv = (const float*)d_in[8];
  const float* bv = (const float*)d_in[9];
  const float* Wo = (const float*)d_in[10];
  const float* bo = (const float*)d_in[11];
  float* out = (float*)d_out;

  char* ws = (char*)d_ws;
  const size_t SZ_X = (size_t)MROWS * DM * 2;   // 16 MB
  const size_t SZ_W = (size_t)DM * DM * 2;      // 2 MB
  unsigned short* wqb = (unsigned short*)(ws + 0);
  unsigned short* wkb = (unsigned short*)(ws + SZ_W);
  unsigned short* wvb = (unsigned short*)(ws + 2*SZ_W);
  unsigned short* wob = (unsigned short*)(ws + 3*SZ_W);
  unsigned short* Qb   = (unsigned short*)(ws + 4*SZ_W);
  unsigned short* Kbuf = (unsigned short*)(ws + 4*SZ_W + SZ_X);
  unsigned short* Vt   = (unsigned short*)(ws + 4*SZ_W + 2*SZ_X);
  unsigned short* attO = (unsigned short*)(ws + 4*SZ_W + 3*SZ_X);  // total 72 MB

  ConvArgs ca;
  ca.src[0] = Wq; ca.src[1] = Wk; ca.src[2] = Wv; ca.src[3] = Wo;
  ca.dst[0] = wqb; ca.dst[1] = wkb; ca.dst[2] = wvb; ca.dst[3] = wob;
  conv_w<<<4096, 256, 0, stream>>>(ca);

  const int NBLK = (MROWS/128) * (DM/128);   // 512, XCD-swizzled in-kernel
  const float qscale = 0.125f * 1.4426950408889634f;   // 1/sqrt(dk) * log2(e)
  gemm_bt<1,1><<<NBLK, 256, 0, stream>>>(value, wvb, bv, (void*)Vt,   1.0f);
  gemm_bt<0,1><<<NBLK, 256, 0, stream>>>(query, wqb, bq, (void*)Qb,   qscale);
  gemm_bt<0,1><<<NBLK, 256, 0, stream>>>(key,   wkb, bk, (void*)Kbuf, 1.0f);

  attn_kernel<<<dim3(64, 8), 512, 0, stream>>>(Qb, Kbuf, Vt, attO);

  gemm_bt<2,0><<<NBLK, 256, 0, stream>>>(attO, wob, bo, (void*)out, 1.0f);
}

// Round 15
// 188.129 us; speedup vs baseline: 1.1184x; 1.1184x over previous
//
#include <hip/hip_runtime.h>
#include <hip/hip_bf16.h>

#define DM 1024
#define NHEADS 16
#define DKH 64
#define BATCH 4
#define SEQ 2048
#define MROWS (BATCH*SEQ)   // 8192

typedef __attribute__((ext_vector_type(8))) short bf16x8;
typedef __attribute__((ext_vector_type(4))) short bf16x4;
typedef __attribute__((ext_vector_type(4))) float f32x4;
typedef __attribute__((ext_vector_type(16))) float f32x16;

#if __has_builtin(__builtin_amdgcn_exp2f)
#define EXP2(x) __builtin_amdgcn_exp2f(x)
#else
#define EXP2(x) exp2f(x)
#endif

__device__ __forceinline__ unsigned short f2bf(float f){
  unsigned u = __float_as_uint(f);
  u += 0x7fffu + ((u >> 16) & 1u);   // RNE
  return (unsigned short)(u >> 16);
}

__device__ __forceinline__ unsigned pk2bf(float lo, float hi){
  union { __hip_bfloat162 h; unsigned u; } c;
  c.h = __float22bfloat162_rn(make_float2(lo, hi));   // v_cvt_pk_bf16_f32 (RNE)
  return c.u;
}

__device__ __forceinline__ bf16x8 cvtA8(float4 a, float4 b){
  union { unsigned u[4]; bf16x8 v; } r;
  r.u[0] = pk2bf(a.x, a.y);
  r.u[1] = pk2bf(a.z, a.w);
  r.u[2] = pk2bf(b.x, b.y);
  r.u[3] = pk2bf(b.z, b.w);
  return r.v;
}

__device__ __forceinline__ void gload16(const unsigned short* g, unsigned short* l){
  __builtin_amdgcn_global_load_lds((const __attribute__((address_space(1))) void*)g,
                                   (__attribute__((address_space(3))) void*)l, 16, 0, 0);
}

// ---------------- fp32 -> bf16 conversion (4 weight matrices only) ----------------
struct ConvArgs { const float* src[4]; unsigned short* dst[4]; };

__global__ __launch_bounds__(256) void conv_w(ConvArgs a){
  const int t = blockIdx.x >> 10;          // 4 tensors x 1024 blocks
  const int boff = blockIdx.x & 1023;
  const float* __restrict__ src = a.src[t];
  unsigned short* __restrict__ dst = a.dst[t];
  const int i = (boff * 256 + threadIdx.x) * 4;
  const float4 v = *reinterpret_cast<const float4*>(src + i);
  ushort4 o;
  o.x = f2bf(v.x); o.y = f2bf(v.y); o.z = f2bf(v.z); o.w = f2bf(v.w);
  *reinterpret_cast<ushort4*>(dst + i) = o;
}

// ---------------- GEMM: C[m,n] = sum_k A[m,k]*W[n,k] + bias[n] ----------------
// ~880 TF each = the m97-structure ceiling for this 128^2 shape; accepted.
template<int MODE, int AFP32>
__global__ __launch_bounds__(256)
void gemm_bt(const void* __restrict__ Av, const unsigned short* __restrict__ Bw,
             const float* __restrict__ bias, void* __restrict__ out, float scale)
{
  const int K = 1024;
  __shared__ short a_sh[128*64];
  __shared__ short b_sh[128*64];
  const int tid  = threadIdx.x;
  const int lane = tid & 63;
  const int wid  = tid >> 6;
  const int wm = wid >> 1, wn = wid & 1;           // 2x2 waves -> 64x64 each
  const int lin = blockIdx.x;
  const int xcd = lin & 7;
  const int i9  = lin >> 3;
  const int tileM = (8*xcd + (i9 >> 3)) * 128;
  const int tileN = (i9 & 7) * 128;

  f32x4 acc[4][4];
  #pragma unroll
  for (int i = 0; i < 4; i++)
    #pragma unroll
    for (int j = 0; j < 4; j++)
      acc[i][j] = (f32x4){0.f,0.f,0.f,0.f};

  const int lr = lane & 15;
  const int lg = lane >> 4;
  const int r8 = lane >> 3, c8 = lane & 7;
  const int srow = 8*wid + r8;                 // + 32j per call
  const int sgrp = (c8 ^ r8) * 8;              // pre-swizzled source column group

  for (int k0 = 0; k0 < K; k0 += 64){
    bf16x8 ra[4];
    if constexpr (AFP32){
      const float* Af = (const float*)Av;
      #pragma unroll
      for (int i = 0; i < 4; i++){
        int v   = tid + 256*i;
        int row = v >> 3;
        int cg  = v & 7;
        const float4 f0 = *reinterpret_cast<const float4*>(Af + (size_t)(tileM+row)*K + k0 + cg*8);
        const float4 f1 = *reinterpret_cast<const float4*>(Af + (size_t)(tileM+row)*K + k0 + cg*8 + 4);
        ra[i] = cvtA8(f0, f1);
      }
    }
    __syncthreads();   // LDS free (consumers of previous tile done)
    #pragma unroll
    for (int j = 0; j < 4; j++){
      gload16(Bw + (size_t)(tileN + srow + 32*j)*K + k0 + sgrp,
              (unsigned short*)&b_sh[(8*wid + 32*j)*64]);
    }
    if constexpr (AFP32){
      #pragma unroll
      for (int i = 0; i < 4; i++){
        int v   = tid + 256*i;
        int row = v >> 3;
        int cg  = v & 7;
        *reinterpret_cast<bf16x8*>(&a_sh[row*64 + ((cg ^ (row & 7)) * 8)]) = ra[i];
      }
    } else {
      const unsigned short* Ab = (const unsigned short*)Av;
      #pragma unroll
      for (int j = 0; j < 4; j++){
        gload16(Ab + (size_t)(tileM + srow + 32*j)*K + k0 + sgrp,
                (unsigned short*)&a_sh[(8*wid + 32*j)*64]);
      }
    }
    __syncthreads();   // drains vmcnt (gload_lds) + lgkm (ds_write)

    #pragma unroll
    for (int kk = 0; kk < 64; kk += 32){
      bf16x8 af[4], bfr[4];
      const int g0 = lg + (kk >> 3);
      #pragma unroll
      for (int fm = 0; fm < 4; fm++){
        int row = wm*64 + fm*16 + lr;
        af[fm] = *reinterpret_cast<const bf16x8*>(&a_sh[row*64 + ((g0 ^ (row & 7)) * 8)]);
      }
      #pragma unroll
      for (int fn = 0; fn < 4; fn++){
        int row = wn*64 + fn*16 + lr;
        bfr[fn] = *reinterpret_cast<const bf16x8*>(&b_sh[row*64 + ((g0 ^ (row & 7)) * 8)]);
      }
      #pragma unroll
      for (int fm = 0; fm < 4; fm++)
        #pragma unroll
        for (int fn = 0; fn < 4; fn++)
          acc[fm][fn] = __builtin_amdgcn_mfma_f32_16x16x32_bf16(af[fm], bfr[fn], acc[fm][fn], 0, 0, 0);
    }
  }

  #pragma unroll
  for (int fm = 0; fm < 4; fm++){
    #pragma unroll
    for (int fn = 0; fn < 4; fn++){
      #pragma unroll
      for (int r = 0; r < 4; r++){
        int m = tileM + wm*64 + fm*16 + lg*4 + r;
        int n = tileN + wn*64 + fn*16 + lr;
        float val = acc[fm][fn][r] + bias[n];
        if (MODE == 0){
          val *= scale;
          int b = m >> 11, s = m & 2047, h = n >> 6, d = n & 63;
          ((unsigned short*)out)[(((size_t)(b*NHEADS + h)*SEQ + s)*DKH + d)] = f2bf(val);
        } else if (MODE == 1){
          int b = m >> 11, s = m & 2047, h = n >> 6, d = n & 63;
          ((unsigned short*)out)[(((size_t)(b*NHEADS + h)*DKH + d)*SEQ + s)] = f2bf(val);
        } else {
          ((float*)out)[(size_t)m*DM + n] = val;
        }
      }
    }
  }
}

// ---------------- flash attention (causal), 32x32 MFMA pipeline (r11 optimum, verbatim) ----------------
// 512-thread block = 8 waves: waves 0-3 own qtile 15-y, waves 4-7 own qtile y.
// Each wave: 32 q-rows via 32x32x16 MFMA. Lane = one q column (lane&31); 16 C-regs
// hold 16 of 32 k-rows (partner lane^32 holds the rest). KVBLK=128 staged per epoch,
// processed as 4x 32-k chunks. exp2 domain; defer-max THR=8; cvt_pk+shfl pack.
// NOTE: source-level reshaping of the softmax/PV region (split-K r12, phase-split
// r13, tree-max/branch-shfl r14) all REGRESSED via codegen perturbation (spill ->
// +12MB FETCH). This arrangement is a verified good compiler basin — do not perturb.
__global__ __launch_bounds__(512, 2)
void attn_kernel(const unsigned short* __restrict__ Q, const unsigned short* __restrict__ Kb,
                 const unsigned short* __restrict__ Vt, unsigned short* __restrict__ Oout)
{
  __shared__ unsigned short k_sh[2][128*64];   // [k row][d], XOR-swizzled 16B groups
  __shared__ unsigned short v_sh[2][64*128];   // [d][k col], XOR-swizzled 16B groups
  const int lane = threadIdx.x & 63;
  const int w    = threadIdx.x >> 6;          // 0..7
  const int q32  = lane & 31;                 // lane's q column
  const int hi   = lane >> 5;                 // half-wave
  const int l7   = lane & 7;                  // swizzle XOR (row&7 == lane&7 for our reads)
  const int bh = blockIdx.x;                  // 0..63
  const int y  = (int)blockIdx.y;             // 0..7
  const int hiT = 15 - y;
  const int myTile = (w < 4) ? hiT : y;       // paired tiles per block
  const int qb0 = myTile * 128;
  const int qw0 = qb0 + (w & 3) * 32;         // wave's first q row
  const int qglob = qw0 + q32;
  const int b = bh >> 4, h = bh & 15;
  const size_t kbase = (size_t)bh * SEQ * DKH;
  const size_t vbase = (size_t)bh * DKH * SEQ;

  // K staging: wave w stages rows 16w..16w+15 (2 calls x 8 rows).
  const int r8 = lane >> 3, c8 = lane & 7;
  const size_t offK0 = (size_t)(16*w + r8)*DKH     + (size_t)((c8 ^ r8) * 8);
  const size_t offK1 = (size_t)(16*w + 8 + r8)*DKH + (size_t)((c8 ^ r8) * 8);
  const int ldsK0 = (16*w)*64, ldsK1 = (16*w + 8)*64;
  // V staging: wave w stages d-rows 8w..8w+7 (2 calls x 4 rows x 16 groups of 16B).
  const int r4 = lane >> 4, c16 = lane & 15;
  const size_t offV0 = (size_t)(8*w + r4)*SEQ     + (size_t)((c16 ^ r4) * 8);
  const size_t offV1 = (size_t)(8*w + 4 + r4)*SEQ + (size_t)((c16 ^ (4 + r4)) * 8);
  const int ldsV0 = (8*w)*128, ldsV1 = (8*w + 4)*128;

  // Q fragments: qf[dblk][j] = Q[qglob][dblk*16 + hi*8 + j]  (B-operand, 4 d-slices)
  bf16x8 qf[4];
  #pragma unroll
  for (int dblk = 0; dblk < 4; dblk++){
    qf[dblk] = *reinterpret_cast<const bf16x8*>(Q + kbase + (size_t)qglob*DKH + dblk*16 + hi*8);
  }

  float mrun = -__builtin_inff();
  float llocal = 0.f;
  f32x16 o0, o1;          // O^T[d][q]: d32-halves, 16 regs each
  #pragma unroll
  for (int r = 0; r < 16; r++){ o0[r] = 0.f; o1[r] = 0.f; }
  f32x16 zero16;
  #pragma unroll
  for (int r = 0; r < 16; r++) zero16[r] = 0.f;

  const int nkb = hiT + 1;   // 128-k epochs; block length set by the heavy tile

#define STAGE(kb_, bf_) do { \
    gload16(Kb + kbase + (size_t)(kb_)*8192 + offK0, (unsigned short*)&k_sh[bf_][ldsK0]); \
    gload16(Kb + kbase + (size_t)(kb_)*8192 + offK1, (unsigned short*)&k_sh[bf_][ldsK1]); \
    gload16(Vt + vbase + (size_t)(kb_)*128  + offV0, (unsigned short*)&v_sh[bf_][ldsV0]); \
    gload16(Vt + vbase + (size_t)(kb_)*128  + offV1, (unsigned short*)&v_sh[bf_][ldsV1]); \
  } while(0)

  STAGE(0, 0);
  __syncthreads();

  for (int kb = 0; kb < nkb; kb++){
    const int buf = kb & 1;
    if (kb + 1 < nkb) STAGE(kb + 1, buf ^ 1);

    const unsigned short* ks = k_sh[buf];
    const unsigned short* vs = v_sh[buf];

    #pragma unroll
    for (int c = 0; c < 4; c++){
      const int base_k = kb*128 + c*32;
      if (base_k <= qw0 + 31){
        // ---- QK^T: S^T[32k][32q] over d=64 (4 slices) ----
        f32x16 st;
        __builtin_amdgcn_s_setprio(1);
        {
          bf16x8 kf0 = *reinterpret_cast<const bf16x8*>(&ks[(c*32 + q32)*64 + (((0*2 + hi) ^ l7) * 8)]);
          st = __builtin_amdgcn_mfma_f32_32x32x16_bf16(kf0, qf[0], zero16, 0, 0, 0);
        }
        #pragma unroll
        for (int dblk = 1; dblk < 4; dblk++){
          bf16x8 kf = *reinterpret_cast<const bf16x8*>(&ks[(c*32 + q32)*64 + (((dblk*2 + hi) ^ l7) * 8)]);
          st = __builtin_amdgcn_mfma_f32_32x32x16_bf16(kf, qf[dblk], st, 0, 0, 0);
        }
        __builtin_amdgcn_s_setprio(0);

        // ---- causal mask (rare branch: only diagonal chunks) ----
        if (base_k + 31 > qw0){
          #pragma unroll
          for (int r = 0; r < 16; r++){
            int kg = base_k + (r & 3) + 8*(r >> 2) + 4*hi;
            if (kg > qglob) st[r] = -__builtin_inff();
          }
        }

        // ---- row max (local 16 + partner half) ----
        float mt = st[0];
        #pragma unroll
        for (int r = 1; r < 16; r++) mt = fmaxf(mt, st[r]);
        mt = fmaxf(mt, __shfl_xor(mt, 32));

        // defer-max (T13): rescale only when tile max grows past THR=8 (log2 units)
        if (__any(mt > mrun + 8.f)){
          const float mnew = fmaxf(mrun, mt);
          const float corr = EXP2(mrun - mnew);   // exp2(-inf)=0 at first chunk
          mrun = mnew;
          #pragma unroll
          for (int r = 0; r < 16; r++){ o0[r] *= corr; o1[r] *= corr; }
          llocal *= corr;
        }

        // ---- exp2 + lane-local l-sum + pack ----
        float p[16];
        #pragma unroll
        for (int r = 0; r < 16; r++) p[r] = EXP2(st[r] - mrun);
        {
          float s0 = (p[0]+p[1]) + (p[2]+p[3]);
          float s1 = (p[4]+p[5]) + (p[6]+p[7]);
          float s2 = (p[8]+p[9]) + (p[10]+p[11]);
          float s3 = (p[12]+p[13]) + (p[14]+p[15]);
          llocal += (s0+s1) + (s2+s3);
        }
        unsigned pkA0 = pk2bf(p[0],  p[1]),  pkA1 = pk2bf(p[2],  p[3]);
        unsigned pkB0 = pk2bf(p[4],  p[5]),  pkB1 = pk2bf(p[6],  p[7]);
        unsigned pkC0 = pk2bf(p[8],  p[9]),  pkC1 = pk2bf(p[10], p[11]);
        unsigned pkD0 = pk2bf(p[12], p[13]), pkD1 = pk2bf(p[14], p[15]);
        unsigned xA0 = __shfl_xor(pkA0, 32), xA1 = __shfl_xor(pkA1, 32);
        unsigned xB0 = __shfl_xor(pkB0, 32), xB1 = __shfl_xor(pkB1, 32);
        unsigned xC0 = __shfl_xor(pkC0, 32), xC1 = __shfl_xor(pkC1, 32);
        unsigned xD0 = __shfl_xor(pkD0, 32), xD1 = __shfl_xor(pkD1, 32);
        const bool lo = (hi == 0);
        union { unsigned u[4]; bf16x8 v; } f0, f1;
        // frag0 rows hi*8+j = k 0..15:  lo: own k0-3 (pkA) + partner k4-7 (xA)
        //                               hi: partner k8-11 (xB) + own k12-15 (pkB)
        f0.u[0] = lo ? pkA0 : xB0;
        f0.u[1] = lo ? pkA1 : xB1;
        f0.u[2] = lo ? xA0  : pkB0;
        f0.u[3] = lo ? xA1  : pkB1;
        // frag1 rows = k 16..31 (same pattern with C/D)
        f1.u[0] = lo ? pkC0 : xD0;
        f1.u[1] = lo ? pkC1 : xD1;
        f1.u[2] = lo ? xC0  : pkD0;
        f1.u[3] = lo ? xC1  : pkD1;

        // ---- PV: O^T[d][q] += V^T[d][k16] * P^T[k16][q], 2 k16 x 2 d32 ----
        __builtin_amdgcn_s_setprio(1);
        #pragma unroll
        for (int k16 = 0; k16 < 2; k16++){
          bf16x8 fr = k16 ? f1.v : f0.v;
          {
            bf16x8 vf = *reinterpret_cast<const bf16x8*>(
                &vs[(0*32 + q32)*128 + (((c*4 + k16*2 + hi) ^ l7) * 8)]);
            o0 = __builtin_amdgcn_mfma_f32_32x32x16_bf16(vf, fr, o0, 0, 0, 0);
          }
          {
            bf16x8 vf = *reinterpret_cast<const bf16x8*>(
                &vs[(1*32 + q32)*128 + (((c*4 + k16*2 + hi) ^ l7) * 8)]);
            o1 = __builtin_amdgcn_mfma_f32_32x32x16_bf16(vf, fr, o1, 0, 0, 0);
          }
        }
        __builtin_amdgcn_s_setprio(0);
      }
    }
    __syncthreads();
  }
#undef STAGE

  // ---- epilogue: lane owns q-row qglob; d = d32*32 + 8*(reg>>2) + 4*hi + (reg&3) ----
  const float l = llocal + __shfl_xor(llocal, 32);
  const float inv = 1.0f / l;
  size_t ob = ((size_t)(b*SEQ + qglob))*DM + h*DKH;
  #pragma unroll
  for (int g = 0; g < 4; g++){
    ushort4 pk;
    pk.x = f2bf(o0[4*g+0]*inv); pk.y = f2bf(o0[4*g+1]*inv);
    pk.z = f2bf(o0[4*g+2]*inv); pk.w = f2bf(o0[4*g+3]*inv);
    *reinterpret_cast<ushort4*>(&Oout[ob + 8*g + 4*hi]) = pk;
    ushort4 pk2;
    pk2.x = f2bf(o1[4*g+0]*inv); pk2.y = f2bf(o1[4*g+1]*inv);
    pk2.z = f2bf(o1[4*g+2]*inv); pk2.w = f2bf(o1[4*g+3]*inv);
    *reinterpret_cast<ushort4*>(&Oout[ob + 32 + 8*g + 4*hi]) = pk2;
  }
}

extern "C" void kernel_launch(void* const* d_in, const int* in_sizes, int n_in,
                              void* d_out, int out_size, void* d_ws, size_t ws_size,
                              hipStream_t stream) {
  const float* query = (const float*)d_in[0];
  const float* key   = (const float*)d_in[1];
  const float* value = (const float*)d_in[2];
  const float* Wq = (const float*)d_in[4];
  const float* bq = (const float*)d_in[5];
  const float* Wk = (const float*)d_in[6];
  const float* bk = (const float*)d_in[7];
  const float* Wv = (const float*)d_in[8];
  const float* bv = (const float*)d_in[9];
  const float* Wo = (const float*)d_in[10];
  const float* bo = (const float*)d_in[11];
  float* out = (float*)d_out;

  char* ws = (char*)d_ws;
  const size_t SZ_X = (size_t)MROWS * DM * 2;   // 16 MB
  const size_t SZ_W = (size_t)DM * DM * 2;      // 2 MB
  unsigned short* wqb = (unsigned short*)(ws + 0);
  unsigned short* wkb = (unsigned short*)(ws + SZ_W);
  unsigned short* wvb = (unsigned short*)(ws + 2*SZ_W);
  unsigned short* wob = (unsigned short*)(ws + 3*SZ_W);
  unsigned short* Qb   = (unsigned short*)(ws + 4*SZ_W);
  unsigned short* Kbuf = (unsigned short*)(ws + 4*SZ_W + SZ_X);
  unsigned short* Vt   = (unsigned short*)(ws + 4*SZ_W + 2*SZ_X);
  unsigned short* attO = (unsigned short*)(ws + 4*SZ_W + 3*SZ_X);  // total 72 MB

  ConvArgs ca;
  ca.src[0] = Wq; ca.src[1] = Wk; ca.src[2] = Wv; ca.src[3] = Wo;
  ca.dst[0] = wqb; ca.dst[1] = wkb; ca.dst[2] = wvb; ca.dst[3] = wob;
  conv_w<<<4096, 256, 0, stream>>>(ca);

  const int NBLK = (MROWS/128) * (DM/128);   // 512, XCD-swizzled in-kernel
  const float qscale = 0.125f * 1.4426950408889634f;   // 1/sqrt(dk) * log2(e)
  gemm_bt<1,1><<<NBLK, 256, 0, stream>>>(value, wvb, bv, (void*)Vt,   1.0f);
  gemm_bt<0,1><<<NBLK, 256, 0, stream>>>(query, wqb, bq, (void*)Qb,   qscale);
  gemm_bt<0,1><<<NBLK, 256, 0, stream>>>(key,   wkb, bk, (void*)Kbuf, 1.0f);

  attn_kernel<<<dim3(64, 8), 512, 0, stream>>>(Qb, Kbuf, Vt, attO);

  gemm_bt<2,0><<<NBLK, 256, 0, stream>>>(attO, wob, bo, (void*)out, 1.0f);
}